// Round 14
// baseline (5564.030 us; speedup 1.0000x reference)
//
#include <hip/hip_runtime.h>
#include <cmath>

#define L_ 512
#define B_ 128
#define D_ 1024
#define H_ 1024
#define PKN (B_ * H_)  // one packed-h buffer: 128K dwords = 512 KB

typedef __attribute__((ext_vector_type(8))) short bf16x8;
typedef __attribute__((ext_vector_type(4))) float f32x4;
typedef __attribute__((ext_vector_type(4))) unsigned uint4v;

static __device__ __forceinline__ unsigned short f32_bf16_rn(float f) {
  unsigned u = __float_as_uint(f);
  u += 0x7FFFu + ((u >> 16) & 1u);
  return (unsigned short)(u >> 16);
}
static __device__ __forceinline__ float bf16_f32(unsigned short h) {
  return __uint_as_float(((unsigned)h) << 16);
}

static __device__ __forceinline__ void pack8(const float4& u, const float4& v,
                                             bf16x8& hi, bf16x8& lo) {
  float f[8] = {u.x, u.y, u.z, u.w, v.x, v.y, v.z, v.w};
#pragma unroll
  for (int i = 0; i < 8; ++i) {
    const unsigned short h = f32_bf16_rn(f[i]);
    hi[i] = (short)h;
    lo[i] = (short)f32_bf16_rn(f[i] - bf16_f32(h));
  }
}

// ---------------------------------------------------------------------------
// Kernel A: xi = x @ Wi^T + bi, split-bf16 3-MFMA. (unchanged — R7-proven)
// ---------------------------------------------------------------------------
__global__ __launch_bounds__(256) void xi_gemm_mfma(
    const float* __restrict__ x, const float* __restrict__ Wi,
    const float* __restrict__ bi, float* __restrict__ out) {
  __shared__ unsigned short Ahi[128 * 32], Alo[128 * 32];
  __shared__ unsigned short Bhi[128 * 32], Blo[128 * 32];
  const int tid = threadIdx.x;
  const int bm = blockIdx.x, bn = blockIdx.y;
  const int lane = tid & 63, wv = tid >> 6;
  const int wm = wv >> 1, wn = wv & 1;

  const float* Ag = x + (size_t)bm * 128 * D_;
  const float* Bg = Wi + (size_t)bn * 128 * D_;

  f32x4 acc[4][4];
#pragma unroll
  for (int mi = 0; mi < 4; ++mi)
#pragma unroll
    for (int nj = 0; nj < 4; ++nj) acc[mi][nj] = (f32x4){0.f, 0.f, 0.f, 0.f};

  const int r = tid >> 1;
  const int h2 = tid & 1;
  const int sw = r & 3;
  const int s0 = (h2 * 2) ^ sw, s1 = (h2 * 2 + 1) ^ sw;
  const int fr = lane & 15, kg = lane >> 4;

  for (int k0 = 0; k0 < D_; k0 += 32) {
    __syncthreads();
    {
      const float* pa = &Ag[(size_t)r * D_ + k0 + h2 * 16];
      const float* pb = &Bg[(size_t)r * D_ + k0 + h2 * 16];
      const float4 a0 = *(const float4*)(pa + 0), a1 = *(const float4*)(pa + 4);
      const float4 a2 = *(const float4*)(pa + 8), a3 = *(const float4*)(pa + 12);
      const float4 b0 = *(const float4*)(pb + 0), b1 = *(const float4*)(pb + 4);
      const float4 b2 = *(const float4*)(pb + 8), b3 = *(const float4*)(pb + 12);
      bf16x8 h, l;
      pack8(a0, a1, h, l);
      *(bf16x8*)&Ahi[r * 32 + s0 * 8] = h;
      *(bf16x8*)&Alo[r * 32 + s0 * 8] = l;
      pack8(a2, a3, h, l);
      *(bf16x8*)&Ahi[r * 32 + s1 * 8] = h;
      *(bf16x8*)&Alo[r * 32 + s1 * 8] = l;
      pack8(b0, b1, h, l);
      *(bf16x8*)&Bhi[r * 32 + s0 * 8] = h;
      *(bf16x8*)&Blo[r * 32 + s0 * 8] = l;
      pack8(b2, b3, h, l);
      *(bf16x8*)&Bhi[r * 32 + s1 * 8] = h;
      *(bf16x8*)&Blo[r * 32 + s1 * 8] = l;
    }
    __syncthreads();

    bf16x8 Ah[4], Al[4], Bh[4], Bl[4];
#pragma unroll
    for (int mi = 0; mi < 4; ++mi) {
      const int row = wm * 64 + mi * 16 + fr;
      const int sl = kg ^ (row & 3);
      Ah[mi] = *(const bf16x8*)&Ahi[row * 32 + sl * 8];
      Al[mi] = *(const bf16x8*)&Alo[row * 32 + sl * 8];
    }
#pragma unroll
    for (int nj = 0; nj < 4; ++nj) {
      const int row = wn * 64 + nj * 16 + fr;
      const int sl = kg ^ (row & 3);
      Bh[nj] = *(const bf16x8*)&Bhi[row * 32 + sl * 8];
      Bl[nj] = *(const bf16x8*)&Blo[row * 32 + sl * 8];
    }
#pragma unroll
    for (int mi = 0; mi < 4; ++mi)
#pragma unroll
      for (int nj = 0; nj < 4; ++nj) {
        acc[mi][nj] = __builtin_amdgcn_mfma_f32_16x16x32_bf16(
            Ah[mi], Bh[nj], acc[mi][nj], 0, 0, 0);
        acc[mi][nj] = __builtin_amdgcn_mfma_f32_16x16x32_bf16(
            Ah[mi], Bl[nj], acc[mi][nj], 0, 0, 0);
        acc[mi][nj] = __builtin_amdgcn_mfma_f32_16x16x32_bf16(
            Al[mi], Bh[nj], acc[mi][nj], 0, 0, 0);
      }
  }

  const int fq = lane >> 4;
#pragma unroll
  for (int nj = 0; nj < 4; ++nj) {
    const int col = bn * 128 + wn * 64 + nj * 16 + fr;
    const float bias = bi[col];
#pragma unroll
    for (int mi = 0; mi < 4; ++mi)
#pragma unroll
      for (int reg = 0; reg < 4; ++reg) {
        const size_t row = (size_t)bm * 128 + wm * 64 + mi * 16 + fq * 4 + reg;
        out[row * H_ + col] = acc[mi][nj][reg] + bias;
      }
  }
}

// ---------------------------------------------------------------------------
// Kernel B v14: h_t = tanh(xi_t + h_{t-1} @ Wh^T + bh)
//
// v13 structure (256 blocks @1/CU, 8 groups x 32, Wh-hi LDS + Wh-lo regs,
// R2-lineage sync skeleton, bypass h loads, no fences) + ONE change:
//
//  * PRODUCER-PACKED h exchange. The finisher packs h as (bf16hi<<16|bf16lo)
//    into a ping-pong dword buffer in d_ws (write buf t&1, read (t-1)&1;
//    the inter-step barrier separates generations). Consumers load 4x64-bit
//    bypass words per k-tile (half the bytes) and unpack with v_perm_b32
//    (8 VALU/kt) instead of pack8 (80 VALU/kt, 32x-redundant across the
//    group's consumer blocks). Bit-identical arithmetic to consumer-side
//    packing. t=0 keeps the f32-h0 + pack8 path. pk stores are the same
//    sc1 write-through atomics, drained by the existing vmcnt(0) publish.
// ---------------------------------------------------------------------------
__global__ __launch_bounds__(256, 1) void rnn_scan(
    const float* __restrict__ h0, const float* __restrict__ Wh,
    const float* __restrict__ bh, float* __restrict__ out,
    unsigned int* __restrict__ flags, unsigned int* __restrict__ pk) {
  __shared__ unsigned short WhHi[32 * 1024];  // 64 KB
  __shared__ float red[2 * 32 * 17];
  const int tid = threadIdx.x;
  const int g = blockIdx.x & 7;
  const int c = blockIdx.x >> 3;
  const int j0 = c << 5;
  const int b0 = g << 4;

  // ---- Stage Wh-hi rows j0..j0+31 into LDS (once) ----
#pragma unroll
  for (int i = 0; i < 16; ++i) {
    const int sid = i * 256 + tid;
    const int jr = sid >> 7;
    const int s = sid & 127;
    const float* p = &Wh[(size_t)(j0 + jr) * H_ + s * 8];
    const float4 u = *(const float4*)(p);
    const float4 v4 = *(const float4*)(p + 4);
    bf16x8 hi, lo;
    pack8(u, v4, hi, lo);
    *(bf16x8*)&WhHi[jr * 1024 + (s ^ (jr & 7)) * 8] = hi;
  }

  const int lane = tid & 63;
  const int wv = tid >> 6;
  const int jh = wv >> 1;
  const int kh = wv & 1;
  const int fr = lane & 15;
  const int kb = lane >> 4;
  const int frx7 = fr & 7;
  const int jrt = (jh * 16 + fr) * 1024;

  // ---- Wh-lo -> registers: 16 k-tiles x 8 bf16 per lane ----
  bf16x8 wlo[16];
  {
    const float* wrow = Wh + (size_t)(j0 + jh * 16 + fr) * H_ + kh * 512;
#pragma unroll
    for (int kt = 0; kt < 16; ++kt) {
      const float* p = wrow + kt * 32 + kb * 8;
      const float4 u = *(const float4*)(p);
      const float4 v4 = *(const float4*)(p + 4);
      bf16x8 hi;
      pack8(u, v4, hi, wlo[kt]);
    }
  }

  const int jf = tid & 31;
  const int bfh = tid >> 5;
  const float bias = bh[j0 + jf];
  unsigned int* gflags = flags + (g << 6);
  __syncthreads();

  const size_t hoffF = (size_t)fr * H_ + kh * 512;  // f32/pk element offset
  const size_t obase0 = (size_t)(b0 + bfh) * H_ + (j0 + jf);
  const size_t obase1 = obase0 + (size_t)8 * H_;
  float xi0 = out[obase0];
  float xi1 = out[obase1];
  for (int t = 0; t < L_; ++t) {
    f32x4 acc = (f32x4){0.f, 0.f, 0.f, 0.f};
    if (t == 0) {
      // f32 h0 + consumer-side pack (original path)
      const unsigned long long* h64 =
          (const unsigned long long*)(h0 + (size_t)b0 * H_);
      const size_t hoff64 = (hoffF >> 1) + kb * 4;
#pragma unroll
      for (int kt = 0; kt < 16; ++kt) {
        const size_t k64 = hoff64 + kt * 16;
        const unsigned long long p0 = __hip_atomic_load(
            &h64[k64 + 0], __ATOMIC_RELAXED, __HIP_MEMORY_SCOPE_AGENT);
        const unsigned long long p1 = __hip_atomic_load(
            &h64[k64 + 1], __ATOMIC_RELAXED, __HIP_MEMORY_SCOPE_AGENT);
        const unsigned long long p2 = __hip_atomic_load(
            &h64[k64 + 2], __ATOMIC_RELAXED, __HIP_MEMORY_SCOPE_AGENT);
        const unsigned long long p3 = __hip_atomic_load(
            &h64[k64 + 3], __ATOMIC_RELAXED, __HIP_MEMORY_SCOPE_AGENT);
        const float4 u = make_float4(__uint_as_float((unsigned)p0),
                                     __uint_as_float((unsigned)(p0 >> 32)),
                                     __uint_as_float((unsigned)p1),
                                     __uint_as_float((unsigned)(p1 >> 32)));
        const float4 v4 = make_float4(__uint_as_float((unsigned)p2),
                                      __uint_as_float((unsigned)(p2 >> 32)),
                                      __uint_as_float((unsigned)p3),
                                      __uint_as_float((unsigned)(p3 >> 32)));
        bf16x8 Bh, Bl;
        pack8(u, v4, Bh, Bl);
        const int ps = (kh * 64 + kt * 4 + kb) ^ frx7;
        const bf16x8 Ah = *(const bf16x8*)&WhHi[jrt + ps * 8];
        acc = __builtin_amdgcn_mfma_f32_16x16x32_bf16(Ah, Bh, acc, 0, 0, 0);
        acc = __builtin_amdgcn_mfma_f32_16x16x32_bf16(Ah, Bl, acc, 0, 0, 0);
        acc = __builtin_amdgcn_mfma_f32_16x16x32_bf16(wlo[kt], Bh, acc, 0, 0, 0);
      }
    } else {
      // producer-packed path: 4x64-bit bypass loads + v_perm unpack per kt
      const unsigned long long* pk64 = (const unsigned long long*)(
          pk + (size_t)((t + 1) & 1) * PKN + (size_t)b0 * H_ + hoffF);
      const size_t pko = (size_t)kb * 4;
#pragma unroll
      for (int kt = 0; kt < 16; ++kt) {
        const size_t k64 = pko + kt * 16;
        const unsigned long long q0 = __hip_atomic_load(
            &pk64[k64 + 0], __ATOMIC_RELAXED, __HIP_MEMORY_SCOPE_AGENT);
        const unsigned long long q1 = __hip_atomic_load(
            &pk64[k64 + 1], __ATOMIC_RELAXED, __HIP_MEMORY_SCOPE_AGENT);
        const unsigned long long q2 = __hip_atomic_load(
            &pk64[k64 + 2], __ATOMIC_RELAXED, __HIP_MEMORY_SCOPE_AGENT);
        const unsigned long long q3 = __hip_atomic_load(
            &pk64[k64 + 3], __ATOMIC_RELAXED, __HIP_MEMORY_SCOPE_AGENT);
        const unsigned u0 = (unsigned)q0, u1 = (unsigned)(q0 >> 32);
        const unsigned u2 = (unsigned)q1, u3 = (unsigned)(q1 >> 32);
        const unsigned u4 = (unsigned)q2, u5 = (unsigned)(q2 >> 32);
        const unsigned u6 = (unsigned)q3, u7 = (unsigned)(q3 >> 32);
        union { uint4v u; bf16x8 v; } ch, cl;
        ch.u.x = __builtin_amdgcn_perm(u1, u0, 0x07060302u);
        ch.u.y = __builtin_amdgcn_perm(u3, u2, 0x07060302u);
        ch.u.z = __builtin_amdgcn_perm(u5, u4, 0x07060302u);
        ch.u.w = __builtin_amdgcn_perm(u7, u6, 0x07060302u);
        cl.u.x = __builtin_amdgcn_perm(u1, u0, 0x05040100u);
        cl.u.y = __builtin_amdgcn_perm(u3, u2, 0x05040100u);
        cl.u.z = __builtin_amdgcn_perm(u5, u4, 0x05040100u);
        cl.u.w = __builtin_amdgcn_perm(u7, u6, 0x05040100u);
        const int ps = (kh * 64 + kt * 4 + kb) ^ frx7;
        const bf16x8 Ah = *(const bf16x8*)&WhHi[jrt + ps * 8];
        acc = __builtin_amdgcn_mfma_f32_16x16x32_bf16(Ah, ch.v, acc, 0, 0, 0);
        acc = __builtin_amdgcn_mfma_f32_16x16x32_bf16(Ah, cl.v, acc, 0, 0, 0);
        acc = __builtin_amdgcn_mfma_f32_16x16x32_bf16(wlo[kt], ch.v, acc, 0, 0, 0);
      }
    }
    const size_t tB = (size_t)t * B_ * H_;
    const size_t nB = tB + (size_t)(t + 1 < L_ ? B_ * H_ : 0);
    const float xin0 = out[nB + obase0];
    const float xin1 = out[nB + obase1];
#pragma unroll
    for (int r4 = 0; r4 < 4; ++r4)
      red[(kh * 32 + jh * 16 + kb * 4 + r4) * 17 + fr] = acc[r4];
    __syncthreads();
    {
      const float s0 = red[(jf) * 17 + bfh] + red[(32 + jf) * 17 + bfh];
      const float s1 = red[(jf) * 17 + bfh + 8] + red[(32 + jf) * 17 + bfh + 8];
      const float v0 = tanhf(s0 + xi0 + bias);
      const float v1 = tanhf(s1 + xi1 + bias);
      __hip_atomic_store(&out[tB + obase0], v0, __ATOMIC_RELAXED,
                         __HIP_MEMORY_SCOPE_AGENT);
      __hip_atomic_store(&out[tB + obase1], v1, __ATOMIC_RELAXED,
                         __HIP_MEMORY_SCOPE_AGENT);
      // producer-side pack into ping-pong buffer (buf = t&1)
      unsigned int* pkw = pk + (size_t)(t & 1) * PKN;
      const unsigned short h0p = f32_bf16_rn(v0);
      const unsigned short l0p = f32_bf16_rn(v0 - bf16_f32(h0p));
      const unsigned short h1p = f32_bf16_rn(v1);
      const unsigned short l1p = f32_bf16_rn(v1 - bf16_f32(h1p));
      __hip_atomic_store(&pkw[obase0], ((unsigned)h0p << 16) | l0p,
                         __ATOMIC_RELAXED, __HIP_MEMORY_SCOPE_AGENT);
      __hip_atomic_store(&pkw[obase1], ((unsigned)h1p << 16) | l1p,
                         __ATOMIC_RELAXED, __HIP_MEMORY_SCOPE_AGENT);
    }

    if (t + 1 < L_) {
      // ---- release: drain (covers out+pk stores), block done, publish ----
      asm volatile("s_waitcnt vmcnt(0)" ::: "memory");
      __syncthreads();
      if (tid == 0)
        __hip_atomic_store(&gflags[c], (unsigned)(t + 1), __ATOMIC_RELAXED,
                           __HIP_MEMORY_SCOPE_AGENT);
      // ---- wave 0: poll the 32 group flags ----
      if (tid < 64) {
        const unsigned tgt = (unsigned)(t + 1);
        while (true) {
          const unsigned f = __hip_atomic_load(&gflags[tid & 31],
                                               __ATOMIC_RELAXED,
                                               __HIP_MEMORY_SCOPE_AGENT);
          if (__all((int)(f >= tgt))) break;
          __builtin_amdgcn_s_sleep(1);
        }
      }
      __syncthreads();
    }
    xi0 = xin0;
    xi1 = xin1;
  }
}

// ---------------------------------------------------------------------------
extern "C" void kernel_launch(void* const* d_in, const int* in_sizes, int n_in,
                              void* d_out, int out_size, void* d_ws, size_t ws_size,
                              hipStream_t stream) {
  const float* x    = (const float*)d_in[0];
  const float* h0   = (const float*)d_in[1];
  const float* Wi_w = (const float*)d_in[2];
  const float* Wi_b = (const float*)d_in[3];
  const float* Wh_w = (const float*)d_in[4];
  const float* Wh_b = (const float*)d_in[5];
  float* out = (float*)d_out;
  unsigned int* flags = (unsigned int*)d_ws;                 // 4 KB
  unsigned int* pk = (unsigned int*)((char*)d_ws + 4096);    // 2 x 512 KB

  // Phase 1: xi -> d_out (split-bf16 MFMA)
  hipLaunchKernelGGL(xi_gemm_mfma, dim3(512, 8), dim3(256), 0, stream,
                     x, Wi_w, Wi_b, out);

  // Zero the barrier flags (graph replays reuse d_ws; flags must start 0)
  hipMemsetAsync(d_ws, 0, 4096, stream);

  // Phase 2: cooperative scan — 256 blocks (1/CU), producer-packed exchange
  void* args[] = { (void*)&h0, (void*)&Wh_w, (void*)&Wh_b, (void*)&out,
                   (void*)&flags, (void*)&pk };
  hipLaunchCooperativeKernel((void*)rnn_scan, dim3(256), dim3(256), args, 0, stream);
}